// Round 1
// baseline (8376.410 us; speedup 1.0000x reference)
//
#include <hip/hip_runtime.h>
#include <hip/hip_bf16.h>

#define L_ 8
#define B_ 8
#define T_ 1024
#define C_ 768
#define H_ 12
#define D_HEAD 64
#define V_ 1024
#define FF_ 3072
#define M_ (B_ * T_)  // 8192 rows

typedef __bf16 bf16x8 __attribute__((ext_vector_type(8)));
typedef float f32x4 __attribute__((ext_vector_type(4)));

typedef const __attribute__((address_space(1))) void* as1cvp;
typedef __attribute__((address_space(3))) void* as3vp;

__device__ __forceinline__ void async16(const void* g, void* l) {
  __builtin_amdgcn_global_load_lds((as1cvp)g, (as3vp)l, 16, 0, 0);
}

__device__ __forceinline__ float bf2f(unsigned short u) {
  union { unsigned u32; float f; } c; c.u32 = ((unsigned)u) << 16; return c.f;
}

__device__ __forceinline__ float gelu_f(float x) {
  return 0.5f * x * (1.0f + erff(x * 0.70710678118654752f));
}

// ---------------------------------------------------------------------------
// Embedding: h[row, c] = embed[x[row]][c] + pos[row % T][c]; also bf16 copy.
// ---------------------------------------------------------------------------
__global__ __launch_bounds__(256) void embed_kernel(
    const int* __restrict__ x, const float* __restrict__ emb,
    const float* __restrict__ pos, float* __restrict__ h,
    __hip_bfloat16* __restrict__ hb) {
  int row = blockIdx.x;
  int t = row & (T_ - 1);
  int id = x[row];
#pragma unroll
  for (int j = 0; j < 3; ++j) {
    int c = threadIdx.x + j * 256;
    float v = emb[(size_t)id * C_ + c] + pos[(size_t)t * C_ + c];
    h[(size_t)row * C_ + c] = v;
    hb[(size_t)row * C_ + c] = __float2bfloat16(v);
  }
}

// ---------------------------------------------------------------------------
// Transpose + cast: W (K x N, f32) -> Wt (N x K, bf16)
// ---------------------------------------------------------------------------
__global__ void transpose_cast(const float* __restrict__ W,
                               __hip_bfloat16* __restrict__ Wt, int K, int N) {
  __shared__ float tile[32][33];
  int nb = blockIdx.x * 32, kb = blockIdx.y * 32;
  int tx = threadIdx.x, ty = threadIdx.y;  // 32 x 8
#pragma unroll
  for (int r = 0; r < 4; ++r)
    tile[ty + r * 8][tx] = W[(size_t)(kb + ty + r * 8) * N + nb + tx];
  __syncthreads();
#pragma unroll
  for (int r = 0; r < 4; ++r)
    Wt[(size_t)(nb + ty + r * 8) * K + kb + tx] =
        __float2bfloat16(tile[tx][ty + r * 8]);
}

// ---------------------------------------------------------------------------
// GEMM: C[M,N] = A[M,K](bf16) @ Bt[N,K](bf16)^T + bias, opt GELU, f32/bf16 out
// 128x128 tile, BK=32, 256 threads (4 waves, 2x2), mfma_f32_16x16x32_bf16.
// ---------------------------------------------------------------------------
template <int ACT_GELU, int OUT_BF16>
__global__ __launch_bounds__(256, 2) void gemm_bt(
    const __hip_bfloat16* __restrict__ A, const __hip_bfloat16* __restrict__ Bt,
    const float* __restrict__ bias, void* __restrict__ Cv, int M, int N, int K) {
  __shared__ __align__(16) __hip_bfloat16 As[128 * 32];
  __shared__ __align__(16) __hip_bfloat16 Bs[128 * 32];
  const int tid = threadIdx.x;
  const int lane = tid & 63, wv = tid >> 6;
  const int lane4 = lane & 15, quad = lane >> 4;
  const int wr = wv >> 1, wc = wv & 1;
  const int bm = blockIdx.y * 128, bn = blockIdx.x * 128;

  // staging: 512 chunks of 16B per tile; thread handles chunks tid and tid+256
  const int r0 = tid >> 2, kc0 = (tid & 3) * 8;
  const __hip_bfloat16* gA0 = A + (size_t)(bm + r0) * K + kc0;
  const __hip_bfloat16* gA1 = gA0 + (size_t)64 * K;
  const __hip_bfloat16* gB0 = Bt + (size_t)(bn + r0) * K + kc0;
  const __hip_bfloat16* gB1 = gB0 + (size_t)64 * K;
  __hip_bfloat16* lA0 = As + tid * 8;
  __hip_bfloat16* lA1 = As + (tid + 256) * 8;
  __hip_bfloat16* lB0 = Bs + tid * 8;
  __hip_bfloat16* lB1 = Bs + (tid + 256) * 8;

  f32x4 acc[4][4] = {};

  for (int k0 = 0; k0 < K; k0 += 32) {
    async16(gA0 + k0, lA0);
    async16(gA1 + k0, lA1);
    async16(gB0 + k0, lB0);
    async16(gB1 + k0, lB1);
    __syncthreads();
    bf16x8 af[4], bfv[4];
#pragma unroll
    for (int i = 0; i < 4; ++i)
      af[i] = *(const bf16x8*)(As + (wr * 64 + i * 16 + lane4) * 32 + quad * 8);
#pragma unroll
    for (int j = 0; j < 4; ++j)
      bfv[j] = *(const bf16x8*)(Bs + (wc * 64 + j * 16 + lane4) * 32 + quad * 8);
#pragma unroll
    for (int i = 0; i < 4; ++i)
#pragma unroll
      for (int j = 0; j < 4; ++j)
        acc[i][j] = __builtin_amdgcn_mfma_f32_16x16x32_bf16(af[i], bfv[j],
                                                            acc[i][j], 0, 0, 0);
    __syncthreads();
  }

  // epilogue: C/D layout col=lane&15, row=quad*4+reg
#pragma unroll
  for (int i = 0; i < 4; ++i) {
    int row0 = bm + wr * 64 + i * 16 + quad * 4;
#pragma unroll
    for (int j = 0; j < 4; ++j) {
      int col = bn + wc * 64 + j * 16 + lane4;
      float bv = bias[col];
#pragma unroll
      for (int r = 0; r < 4; ++r) {
        float v = acc[i][j][r] + bv;
        if (ACT_GELU) v = gelu_f(v);
        size_t off = (size_t)(row0 + r) * N + col;
        if (OUT_BF16)
          ((__hip_bfloat16*)Cv)[off] = __float2bfloat16(v);
        else
          ((float*)Cv)[off] = v;
      }
    }
  }
}

// ---------------------------------------------------------------------------
// Causal attention, fp32 compute, bf16 qkv in (order K,Q,V), bf16 y out.
// One block = 64 queries of one (b, head). Online softmax.
// Thread: q = tid>>2, owns dims [ (tid&3)*16, +16 ).
// ---------------------------------------------------------------------------
__global__ __launch_bounds__(256) void attn_kernel(
    const __hip_bfloat16* __restrict__ qkv, __hip_bfloat16* __restrict__ y) {
  __shared__ __align__(16) float Kt[64][68];
  __shared__ __align__(16) float Vt[64][68];
  __shared__ __align__(16) float S[64][68];

  const int tid = threadIdx.x;
  const int qt = gridDim.x - 1 - blockIdx.x;  // heavy tiles launch first
  const int bh = blockIdx.y;
  const int b = bh / H_, hh = bh % H_;
  const int q = tid >> 2, quarter = tid & 3, dlo = quarter * 16;
  const unsigned short* qk = (const unsigned short*)qkv;
  const size_t baseBH = (size_t)b * T_ * (3 * C_) + hh * D_HEAD;

  float Qr[16];
  {
    const unsigned short* qp =
        qk + baseBH + (size_t)(qt * 64 + q) * (3 * C_) + C_ + dlo;
#pragma unroll
    for (int j = 0; j < 16; ++j) Qr[j] = bf2f(qp[j]) * 0.125f;
  }

  float acc[16];
#pragma unroll
  for (int j = 0; j < 16; ++j) acc[j] = 0.f;
  float m = -INFINITY, l = 0.f;

  const int srow = tid >> 2, sseg = tid & 3;
  const int gq = qt * 64 + q;

  for (int kt = 0; kt <= qt; ++kt) {
    __syncthreads();  // protect Kt/Vt/S from previous iteration readers
    {
      const unsigned short* kp =
          qk + baseBH + (size_t)(kt * 64 + srow) * (3 * C_) + sseg * 16;
      const unsigned short* vp = kp + 2 * C_;
      union { uint4 v[2]; unsigned short s[16]; } kb_, vb_;
      kb_.v[0] = *(const uint4*)kp;
      kb_.v[1] = *((const uint4*)kp + 1);
      vb_.v[0] = *(const uint4*)vp;
      vb_.v[1] = *((const uint4*)vp + 1);
      float4* kd = (float4*)&Kt[srow][sseg * 16];
      float4* vd = (float4*)&Vt[srow][sseg * 16];
#pragma unroll
      for (int c = 0; c < 4; ++c) {
        kd[c] = make_float4(bf2f(kb_.s[c * 4]), bf2f(kb_.s[c * 4 + 1]),
                            bf2f(kb_.s[c * 4 + 2]), bf2f(kb_.s[c * 4 + 3]));
        vd[c] = make_float4(bf2f(vb_.s[c * 4]), bf2f(vb_.s[c * 4 + 1]),
                            bf2f(vb_.s[c * 4 + 2]), bf2f(vb_.s[c * 4 + 3]));
      }
    }
    __syncthreads();

    // scores: s[q][k] for all 64 k (partial dot over 16 dims + 4-lane reduce)
#pragma unroll 4
    for (int k = 0; k < 64; ++k) {
      const float4* kv4 = (const float4*)&Kt[k][dlo];
      float4 c0 = kv4[0], c1 = kv4[1], c2 = kv4[2], c3 = kv4[3];
      float p = Qr[0] * c0.x + Qr[1] * c0.y + Qr[2] * c0.z + Qr[3] * c0.w +
                Qr[4] * c1.x + Qr[5] * c1.y + Qr[6] * c1.z + Qr[7] * c1.w +
                Qr[8] * c2.x + Qr[9] * c2.y + Qr[10] * c2.z + Qr[11] * c2.w +
                Qr[12] * c3.x + Qr[13] * c3.y + Qr[14] * c3.z + Qr[15] * c3.w;
      p += __shfl_xor(p, 1);
      p += __shfl_xor(p, 2);
      float s = ((kt * 64 + k) <= gq) ? p : -1e30f;
      if (quarter == 0) S[q][k] = s;
    }
    __syncthreads();

    // online softmax update for this tile
    float sv[16];
#pragma unroll
    for (int j = 0; j < 16; ++j) sv[j] = S[q][quarter * 16 + j];
    float tm = sv[0];
#pragma unroll
    for (int j = 1; j < 16; ++j) tm = fmaxf(tm, sv[j]);
    tm = fmaxf(tm, __shfl_xor(tm, 1));
    tm = fmaxf(tm, __shfl_xor(tm, 2));
    float mn = fmaxf(m, tm);
    float alpha = __expf(m - mn);  // m = -inf on first tile -> alpha = 0
    float ts = 0.f;
#pragma unroll
    for (int j = 0; j < 16; ++j) {
      float p = __expf(sv[j] - mn);
      ts += p;
      S[q][quarter * 16 + j] = p;
    }
    ts += __shfl_xor(ts, 1);
    ts += __shfl_xor(ts, 2);
    l = l * alpha + ts;
    m = mn;
#pragma unroll
    for (int j = 0; j < 16; ++j) acc[j] *= alpha;
    __syncthreads();

    // PV accumulate
#pragma unroll 4
    for (int k = 0; k < 64; ++k) {
      float p = S[q][k];
      const float4* vv = (const float4*)&Vt[k][dlo];
      float4 w0 = vv[0], w1 = vv[1], w2 = vv[2], w3 = vv[3];
      acc[0] += p * w0.x;  acc[1] += p * w0.y;
      acc[2] += p * w0.z;  acc[3] += p * w0.w;
      acc[4] += p * w1.x;  acc[5] += p * w1.y;
      acc[6] += p * w1.z;  acc[7] += p * w1.w;
      acc[8] += p * w2.x;  acc[9] += p * w2.y;
      acc[10] += p * w2.z; acc[11] += p * w2.w;
      acc[12] += p * w3.x; acc[13] += p * w3.y;
      acc[14] += p * w3.z; acc[15] += p * w3.w;
    }
  }

  float inv = 1.f / l;
  __hip_bfloat16* yp =
      y + (size_t)(b * T_ + qt * 64 + q) * C_ + hh * D_HEAD + dlo;
#pragma unroll
  for (int j = 0; j < 16; ++j) yp[j] = __float2bfloat16(acc[j] * inv);
}

// ---------------------------------------------------------------------------
// h = h + LayerNorm(z) * g + beta ; also write bf16 copy of updated h.
// One block per row (C=768 = 3*256).
// ---------------------------------------------------------------------------
__global__ __launch_bounds__(256) void resid_ln(
    float* __restrict__ h, const float* __restrict__ z,
    const float* __restrict__ g, const float* __restrict__ be,
    __hip_bfloat16* __restrict__ hb) {
  int row = blockIdx.x;
  int tid = threadIdx.x;
  const float* zr = z + (size_t)row * C_;
  float v[3], s = 0.f, s2 = 0.f;
#pragma unroll
  for (int j = 0; j < 3; ++j) {
    v[j] = zr[tid + 256 * j];
    s += v[j];
    s2 += v[j] * v[j];
  }
#pragma unroll
  for (int msk = 1; msk < 64; msk <<= 1) {
    s += __shfl_xor(s, msk);
    s2 += __shfl_xor(s2, msk);
  }
  __shared__ float red[8];
  int w = tid >> 6;
  if ((tid & 63) == 0) { red[w] = s; red[4 + w] = s2; }
  __syncthreads();
  s = red[0] + red[1] + red[2] + red[3];
  s2 = red[4] + red[5] + red[6] + red[7];
  float mu = s * (1.f / C_);
  float var = s2 * (1.f / C_) - mu * mu;
  float rstd = rsqrtf(var + 1e-5f);
  float* hr = h + (size_t)row * C_;
  __hip_bfloat16* hbr = hb + (size_t)row * C_;
#pragma unroll
  for (int j = 0; j < 3; ++j) {
    int c = tid + 256 * j;
    float nv = hr[c] + (v[j] - mu) * rstd * g[c] + be[c];
    hr[c] = nv;
    hbr[c] = __float2bfloat16(nv);
  }
}

// ---------------------------------------------------------------------------
extern "C" void kernel_launch(void* const* d_in, const int* in_sizes, int n_in,
                              void* d_out, int out_size, void* d_ws,
                              size_t ws_size, hipStream_t stream) {
  const int* x = (const int*)d_in[0];
  const float* embed = (const float*)d_in[1];
  const float* pos = (const float*)d_in[2];
  const float* Wqkv = (const float*)d_in[3];
  const float* bqkv = (const float*)d_in[4];
  const float* W1a = (const float*)d_in[5];
  const float* b1a = (const float*)d_in[6];
  const float* W2a = (const float*)d_in[7];
  const float* b2a = (const float*)d_in[8];
  const float* g1 = (const float*)d_in[9];
  const float* be1 = (const float*)d_in[10];
  const float* W1b = (const float*)d_in[11];
  const float* b1b = (const float*)d_in[12];
  const float* W2b = (const float*)d_in[13];
  const float* b2b = (const float*)d_in[14];
  const float* g2 = (const float*)d_in[15];
  const float* be2 = (const float*)d_in[16];
  const float* lmW = (const float*)d_in[17];
  const float* lmb = (const float*)d_in[18];
  float* out = (float*)d_out;

  char* p = (char*)d_ws;
  auto alloc = [&](size_t bytes) {
    void* r = (void*)p;
    p += (bytes + 255) & ~(size_t)255;
    return r;
  };
  float* h = (float*)alloc((size_t)M_ * C_ * 4);
  __hip_bfloat16* hb = (__hip_bfloat16*)alloc((size_t)M_ * C_ * 2);
  __hip_bfloat16* qkv = (__hip_bfloat16*)alloc((size_t)M_ * 3 * C_ * 2);
  __hip_bfloat16* ybuf = (__hip_bfloat16*)alloc((size_t)M_ * C_ * 2);
  __hip_bfloat16* ubuf = (__hip_bfloat16*)alloc((size_t)M_ * FF_ * 2);
  float* zbuf = (float*)alloc((size_t)M_ * C_ * 4);
  __hip_bfloat16* Wt = (__hip_bfloat16*)alloc((size_t)FF_ * C_ * 2);

  dim3 blk256(256);
  embed_kernel<<<M_, blk256, 0, stream>>>(x, embed, pos, h, hb);

  for (int l = 0; l < L_; ++l) {
    // qkv = h @ Wqkv + bqkv  (bf16 out)
    transpose_cast<<<dim3(3 * C_ / 32, C_ / 32), dim3(32, 8), 0, stream>>>(
        Wqkv + (size_t)l * C_ * 3 * C_, Wt, C_, 3 * C_);
    gemm_bt<0, 1><<<dim3(3 * C_ / 128, M_ / 128), blk256, 0, stream>>>(
        hb, Wt, bqkv + (size_t)l * 3 * C_, qkv, M_, 3 * C_, C_);
    // attention -> ybuf (bf16)
    attn_kernel<<<dim3(T_ / 64, B_ * H_), blk256, 0, stream>>>(qkv, ybuf);
    // FFN a: u = gelu(y @ W1a + b1a)  (bf16)
    transpose_cast<<<dim3(FF_ / 32, C_ / 32), dim3(32, 8), 0, stream>>>(
        W1a + (size_t)l * C_ * FF_, Wt, C_, FF_);
    gemm_bt<1, 1><<<dim3(FF_ / 128, M_ / 128), blk256, 0, stream>>>(
        ybuf, Wt, b1a + (size_t)l * FF_, ubuf, M_, FF_, C_);
    // z = u @ W2a + b2a  (f32)
    transpose_cast<<<dim3(C_ / 32, FF_ / 32), dim3(32, 8), 0, stream>>>(
        W2a + (size_t)l * FF_ * C_, Wt, FF_, C_);
    gemm_bt<0, 0><<<dim3(C_ / 128, M_ / 128), blk256, 0, stream>>>(
        ubuf, Wt, b2a + (size_t)l * C_, zbuf, M_, C_, FF_);
    // h += LN(z)
    resid_ln<<<M_, blk256, 0, stream>>>(h, zbuf, g1 + (size_t)l * C_,
                                        be1 + (size_t)l * C_, hb);
    // FFN b on updated h
    transpose_cast<<<dim3(FF_ / 32, C_ / 32), dim3(32, 8), 0, stream>>>(
        W1b + (size_t)l * C_ * FF_, Wt, C_, FF_);
    gemm_bt<1, 1><<<dim3(FF_ / 128, M_ / 128), blk256, 0, stream>>>(
        hb, Wt, b1b + (size_t)l * FF_, ubuf, M_, FF_, C_);
    transpose_cast<<<dim3(C_ / 32, FF_ / 32), dim3(32, 8), 0, stream>>>(
        W2b + (size_t)l * FF_ * C_, Wt, FF_, C_);
    gemm_bt<0, 0><<<dim3(C_ / 128, M_ / 128), blk256, 0, stream>>>(
        ubuf, Wt, b2b + (size_t)l * C_, zbuf, M_, C_, FF_);
    resid_ln<<<M_, blk256, 0, stream>>>(h, zbuf, g2 + (size_t)l * C_,
                                        be2 + (size_t)l * C_, hb);
  }

  // logits = h @ lm_W + lm_b  (f32 out)
  transpose_cast<<<dim3(V_ / 32, C_ / 32), dim3(32, 8), 0, stream>>>(
      lmW, Wt, C_, V_);
  gemm_bt<0, 0><<<dim3(V_ / 128, M_ / 128), blk256, 0, stream>>>(
      hb, Wt, lmb, out, M_, V_, C_);
}

// Round 2
// 4191.781 us; speedup vs baseline: 1.9983x; 1.9983x over previous
//
#include <hip/hip_runtime.h>
#include <hip/hip_bf16.h>

#define L_ 8
#define B_ 8
#define T_ 1024
#define C_ 768
#define H_ 12
#define D_HEAD 64
#define V_ 1024
#define FF_ 3072
#define M_ (B_ * T_)  // 8192 rows

typedef __bf16 bf16x8 __attribute__((ext_vector_type(8)));
typedef float f32x4 __attribute__((ext_vector_type(4)));

typedef const __attribute__((address_space(1))) void* as1cvp;
typedef __attribute__((address_space(3))) void* as3vp;

__device__ __forceinline__ void async16(const void* g, void* l) {
  __builtin_amdgcn_global_load_lds((as1cvp)g, (as3vp)l, 16, 0, 0);
}

__device__ __forceinline__ float bf2f(unsigned short u) {
  union { unsigned u32; float f; } c; c.u32 = ((unsigned)u) << 16; return c.f;
}

__device__ __forceinline__ unsigned short f2bf(float f) {
  __hip_bfloat16 h = __float2bfloat16(f);
  return *(unsigned short*)&h;
}

__device__ __forceinline__ float gelu_f(float x) {
  return 0.5f * x * (1.0f + erff(x * 0.70710678118654752f));
}

// ---------------------------------------------------------------------------
// Embedding: h[row, c] = embed[x[row]][c] + pos[row % T][c]; also bf16 copy.
// ---------------------------------------------------------------------------
__global__ __launch_bounds__(256) void embed_kernel(
    const int* __restrict__ x, const float* __restrict__ emb,
    const float* __restrict__ pos, float* __restrict__ h,
    __hip_bfloat16* __restrict__ hb) {
  int row = blockIdx.x;
  int t = row & (T_ - 1);
  int id = x[row];
#pragma unroll
  for (int j = 0; j < 3; ++j) {
    int c = threadIdx.x + j * 256;
    float v = emb[(size_t)id * C_ + c] + pos[(size_t)t * C_ + c];
    h[(size_t)row * C_ + c] = v;
    hb[(size_t)row * C_ + c] = __float2bfloat16(v);
  }
}

// ---------------------------------------------------------------------------
// Transpose + cast: W (K x N, f32) -> Wt (N x K, bf16)
// ---------------------------------------------------------------------------
__global__ void transpose_cast(const float* __restrict__ W,
                               __hip_bfloat16* __restrict__ Wt, int K, int N) {
  __shared__ float tile[32][33];
  int nb = blockIdx.x * 32, kb = blockIdx.y * 32;
  int tx = threadIdx.x, ty = threadIdx.y;  // 32 x 8
#pragma unroll
  for (int r = 0; r < 4; ++r)
    tile[ty + r * 8][tx] = W[(size_t)(kb + ty + r * 8) * N + nb + tx];
  __syncthreads();
#pragma unroll
  for (int r = 0; r < 4; ++r)
    Wt[(size_t)(nb + ty + r * 8) * K + kb + tx] =
        __float2bfloat16(tile[tx][ty + r * 8]);
}

// ---------------------------------------------------------------------------
// GEMM: C[M,N] = A[M,K](bf16) @ Bt[N,K](bf16)^T + bias, opt GELU, f32/bf16 out
// 128x128 tile, BK=32, 256 threads (4 waves, 2x2), mfma_f32_16x16x32_bf16.
// ---------------------------------------------------------------------------
template <int ACT_GELU, int OUT_BF16>
__global__ __launch_bounds__(256, 2) void gemm_bt(
    const __hip_bfloat16* __restrict__ A, const __hip_bfloat16* __restrict__ Bt,
    const float* __restrict__ bias, void* __restrict__ Cv, int M, int N, int K) {
  __shared__ __align__(16) __hip_bfloat16 As[128 * 32];
  __shared__ __align__(16) __hip_bfloat16 Bs[128 * 32];
  const int tid = threadIdx.x;
  const int lane = tid & 63, wv = tid >> 6;
  const int lane4 = lane & 15, quad = lane >> 4;
  const int wr = wv >> 1, wc = wv & 1;
  const int bm = blockIdx.y * 128, bn = blockIdx.x * 128;

  const int r0 = tid >> 2, kc0 = (tid & 3) * 8;
  const __hip_bfloat16* gA0 = A + (size_t)(bm + r0) * K + kc0;
  const __hip_bfloat16* gA1 = gA0 + (size_t)64 * K;
  const __hip_bfloat16* gB0 = Bt + (size_t)(bn + r0) * K + kc0;
  const __hip_bfloat16* gB1 = gB0 + (size_t)64 * K;
  __hip_bfloat16* lA0 = As + tid * 8;
  __hip_bfloat16* lA1 = As + (tid + 256) * 8;
  __hip_bfloat16* lB0 = Bs + tid * 8;
  __hip_bfloat16* lB1 = Bs + (tid + 256) * 8;

  f32x4 acc[4][4] = {};

  for (int k0 = 0; k0 < K; k0 += 32) {
    async16(gA0 + k0, lA0);
    async16(gA1 + k0, lA1);
    async16(gB0 + k0, lB0);
    async16(gB1 + k0, lB1);
    __syncthreads();
    bf16x8 af[4], bfv[4];
#pragma unroll
    for (int i = 0; i < 4; ++i)
      af[i] = *(const bf16x8*)(As + (wr * 64 + i * 16 + lane4) * 32 + quad * 8);
#pragma unroll
    for (int j = 0; j < 4; ++j)
      bfv[j] = *(const bf16x8*)(Bs + (wc * 64 + j * 16 + lane4) * 32 + quad * 8);
#pragma unroll
    for (int i = 0; i < 4; ++i)
#pragma unroll
      for (int j = 0; j < 4; ++j)
        acc[i][j] = __builtin_amdgcn_mfma_f32_16x16x32_bf16(af[i], bfv[j],
                                                            acc[i][j], 0, 0, 0);
    __syncthreads();
  }

#pragma unroll
  for (int i = 0; i < 4; ++i) {
    int row0 = bm + wr * 64 + i * 16 + quad * 4;
#pragma unroll
    for (int j = 0; j < 4; ++j) {
      int col = bn + wc * 64 + j * 16 + lane4;
      float bv = bias[col];
#pragma unroll
      for (int r = 0; r < 4; ++r) {
        float v = acc[i][j][r] + bv;
        if (ACT_GELU) v = gelu_f(v);
        size_t off = (size_t)(row0 + r) * N + col;
        if (OUT_BF16)
          ((__hip_bfloat16*)Cv)[off] = __float2bfloat16(v);
        else
          ((float*)Cv)[off] = v;
      }
    }
  }
}

// ---------------------------------------------------------------------------
// MFMA flash attention. qkv bf16 (order K,Q,V along last dim), y bf16.
// Block = 64 queries of one (b,head); 4 waves x 16 queries.
// Per k-tile (64 keys): QK^T via mfma (K read from global), online softmax
// in regs, P->LDS (bf16), V->LDS transposed, PV via mfma.
// Layouts (verified): A/B frag [idx=lane&15][k=quad*8+j]; C/D col=lane&15,
// row=quad*4+reg.
// ---------------------------------------------------------------------------
__global__ __launch_bounds__(256) void attn_mfma(
    const __hip_bfloat16* __restrict__ qkv, __hip_bfloat16* __restrict__ y) {
  __shared__ __align__(16) __hip_bfloat16 VtS[64][72];    // [dim][key]
  __shared__ __align__(16) __hip_bfloat16 Ps[4][16][72];  // per wave [q][key]

  const int tid = threadIdx.x;
  const int lane = tid & 63, w = tid >> 6;
  const int lane4 = lane & 15, quad = lane >> 4;
  const int qt = gridDim.x - 1 - blockIdx.x;  // heavy tiles first
  const int bh = blockIdx.y;
  const int b = bh / H_, hh = bh % H_;
  const unsigned short* qk16 = (const unsigned short*)qkv;
  const size_t base = (size_t)b * T_ * (3 * C_) + hh * D_HEAD;

  union FragU { bf16x8 v; unsigned short s[8]; uint4 q; };

  // Q fragment (A operand), rows = qt*64 + w*16 + lane4, pre-scaled by 1/8
  FragU aq[2];
  {
    const unsigned short* qp =
        qk16 + base + (size_t)(qt * 64 + w * 16 + lane4) * (3 * C_) + C_ +
        quad * 8;
#pragma unroll
    for (int c = 0; c < 2; ++c) {
      FragU t;
      t.q = *(const uint4*)(qp + c * 32);
#pragma unroll
      for (int j = 0; j < 8; ++j) aq[c].s[j] = f2bf(bf2f(t.s[j]) * 0.125f);
    }
  }

  f32x4 o_acc[4] = {};
  float m_r[4] = {-1e30f, -1e30f, -1e30f, -1e30f};
  float l_r[4] = {0.f, 0.f, 0.f, 0.f};

  for (int kt = 0; kt <= qt; ++kt) {
    // --- V tile load: key = lane, dims [w*16, +16) ---
    uint4 vld0, vld1;
    {
      const unsigned short* vp =
          qk16 + base + (size_t)(kt * 64 + lane) * (3 * C_) + 2 * C_ + w * 16;
      vld0 = *(const uint4*)vp;
      vld1 = *(const uint4*)(vp + 8);
    }

    // --- S = Q K^T (K rows straight from global; L1/L2-cached) ---
    f32x4 s_acc[4] = {};
#pragma unroll
    for (int nt = 0; nt < 4; ++nt) {
      const unsigned short* kpr =
          qk16 + base + (size_t)(kt * 64 + nt * 16 + lane4) * (3 * C_) +
          quad * 8;
      FragU b0, b1;
      b0.q = *(const uint4*)kpr;
      b1.q = *(const uint4*)(kpr + 32);
      s_acc[nt] = __builtin_amdgcn_mfma_f32_16x16x32_bf16(aq[0].v, b0.v,
                                                          s_acc[nt], 0, 0, 0);
      s_acc[nt] = __builtin_amdgcn_mfma_f32_16x16x32_bf16(aq[1].v, b1.v,
                                                          s_acc[nt], 0, 0, 0);
    }

    // --- causal mask (diagonal tile only) ---
    if (kt == qt) {
      int qloc = w * 16 + quad * 4;  // + r
#pragma unroll
      for (int nt = 0; nt < 4; ++nt) {
        int kloc = nt * 16 + lane4;
#pragma unroll
        for (int r = 0; r < 4; ++r)
          if (kloc > qloc + r) s_acc[nt][r] = -1e30f;
      }
    }

    // --- online softmax (each lane: rows quad*4+r, replicated over lane4) ---
    float p[4][4], alpha[4], ts[4];
#pragma unroll
    for (int r = 0; r < 4; ++r) {
      float tm = fmaxf(fmaxf(s_acc[0][r], s_acc[1][r]),
                       fmaxf(s_acc[2][r], s_acc[3][r]));
      tm = fmaxf(tm, __shfl_xor(tm, 1));
      tm = fmaxf(tm, __shfl_xor(tm, 2));
      tm = fmaxf(tm, __shfl_xor(tm, 4));
      tm = fmaxf(tm, __shfl_xor(tm, 8));
      float mn = fmaxf(m_r[r], tm);
      alpha[r] = __expf(m_r[r] - mn);
      m_r[r] = mn;
      float sr = 0.f;
#pragma unroll
      for (int nt = 0; nt < 4; ++nt) {
        float pv = __expf(s_acc[nt][r] - mn);
        p[nt][r] = pv;
        sr += pv;
      }
      sr += __shfl_xor(sr, 1);
      sr += __shfl_xor(sr, 2);
      sr += __shfl_xor(sr, 4);
      sr += __shfl_xor(sr, 8);
      ts[r] = sr;
    }
#pragma unroll
    for (int r = 0; r < 4; ++r) {
      l_r[r] = l_r[r] * alpha[r] + ts[r];
#pragma unroll
      for (int nt = 0; nt < 4; ++nt) o_acc[nt][r] *= alpha[r];
    }

    __syncthreads();  // prior PV reads of VtS/Ps complete

    // --- write V^T and P to LDS ---
    {
      const unsigned short* vs = (const unsigned short*)&vld0;
#pragma unroll
      for (int j = 0; j < 8; ++j) {
        unsigned short* d = (unsigned short*)&VtS[w * 16 + j][lane];
        *d = vs[j];
      }
      vs = (const unsigned short*)&vld1;
#pragma unroll
      for (int j = 0; j < 8; ++j) {
        unsigned short* d = (unsigned short*)&VtS[w * 16 + 8 + j][lane];
        *d = vs[j];
      }
    }
#pragma unroll
    for (int nt = 0; nt < 4; ++nt)
#pragma unroll
      for (int r = 0; r < 4; ++r) {
        unsigned short* d =
            (unsigned short*)&Ps[w][quad * 4 + r][nt * 16 + lane4];
        *d = f2bf(p[nt][r]);
      }

    __syncthreads();  // VtS visible to all waves

    // --- O += P V ---
    FragU ap0, ap1;
    ap0.v = *(const bf16x8*)&Ps[w][lane4][quad * 8];
    ap1.v = *(const bf16x8*)&Ps[w][lane4][32 + quad * 8];
#pragma unroll
    for (int nt = 0; nt < 4; ++nt) {
      bf16x8 bv0 = *(const bf16x8*)&VtS[nt * 16 + lane4][quad * 8];
      bf16x8 bv1 = *(const bf16x8*)&VtS[nt * 16 + lane4][32 + quad * 8];
      o_acc[nt] = __builtin_amdgcn_mfma_f32_16x16x32_bf16(ap0.v, bv0,
                                                          o_acc[nt], 0, 0, 0);
      o_acc[nt] = __builtin_amdgcn_mfma_f32_16x16x32_bf16(ap1.v, bv1,
                                                          o_acc[nt], 0, 0, 0);
    }
  }

  // --- epilogue: y[q][hh*64 + dim] = O / l ---
  float inv[4];
#pragma unroll
  for (int r = 0; r < 4; ++r) inv[r] = 1.f / l_r[r];
#pragma unroll
  for (int nt = 0; nt < 4; ++nt) {
#pragma unroll
    for (int r = 0; r < 4; ++r) {
      int row = qt * 64 + w * 16 + quad * 4 + r;
      __hip_bfloat16* yp =
          y + (size_t)(b * T_ + row) * C_ + hh * D_HEAD + nt * 16 + lane4;
      *yp = __float2bfloat16(o_acc[nt][r] * inv[r]);
    }
  }
}

// ---------------------------------------------------------------------------
// h = h + LayerNorm(z) * g + beta ; also write bf16 copy of updated h.
// ---------------------------------------------------------------------------
__global__ __launch_bounds__(256) void resid_ln(
    float* __restrict__ h, const float* __restrict__ z,
    const float* __restrict__ g, const float* __restrict__ be,
    __hip_bfloat16* __restrict__ hb) {
  int row = blockIdx.x;
  int tid = threadIdx.x;
  const float* zr = z + (size_t)row * C_;
  float v[3], s = 0.f, s2 = 0.f;
#pragma unroll
  for (int j = 0; j < 3; ++j) {
    v[j] = zr[tid + 256 * j];
    s += v[j];
    s2 += v[j] * v[j];
  }
#pragma unroll
  for (int msk = 1; msk < 64; msk <<= 1) {
    s += __shfl_xor(s, msk);
    s2 += __shfl_xor(s2, msk);
  }
  __shared__ float red[8];
  int w = tid >> 6;
  if ((tid & 63) == 0) { red[w] = s; red[4 + w] = s2; }
  __syncthreads();
  s = red[0] + red[1] + red[2] + red[3];
  s2 = red[4] + red[5] + red[6] + red[7];
  float mu = s * (1.f / C_);
  float var = s2 * (1.f / C_) - mu * mu;
  float rstd = rsqrtf(var + 1e-5f);
  float* hr = h + (size_t)row * C_;
  __hip_bfloat16* hbr = hb + (size_t)row * C_;
#pragma unroll
  for (int j = 0; j < 3; ++j) {
    int c = tid + 256 * j;
    float nv = hr[c] + (v[j] - mu) * rstd * g[c] + be[c];
    hr[c] = nv;
    hbr[c] = __float2bfloat16(nv);
  }
}

// ---------------------------------------------------------------------------
extern "C" void kernel_launch(void* const* d_in, const int* in_sizes, int n_in,
                              void* d_out, int out_size, void* d_ws,
                              size_t ws_size, hipStream_t stream) {
  const int* x = (const int*)d_in[0];
  const float* embed = (const float*)d_in[1];
  const float* pos = (const float*)d_in[2];
  const float* Wqkv = (const float*)d_in[3];
  const float* bqkv = (const float*)d_in[4];
  const float* W1a = (const float*)d_in[5];
  const float* b1a = (const float*)d_in[6];
  const float* W2a = (const float*)d_in[7];
  const float* b2a = (const float*)d_in[8];
  const float* g1 = (const float*)d_in[9];
  const float* be1 = (const float*)d_in[10];
  const float* W1b = (const float*)d_in[11];
  const float* b1b = (const float*)d_in[12];
  const float* W2b = (const float*)d_in[13];
  const float* b2b = (const float*)d_in[14];
  const float* g2 = (const float*)d_in[15];
  const float* be2 = (const float*)d_in[16];
  const float* lmW = (const float*)d_in[17];
  const float* lmb = (const float*)d_in[18];
  float* out = (float*)d_out;

  char* p = (char*)d_ws;
  auto alloc = [&](size_t bytes) {
    void* r = (void*)p;
    p += (bytes + 255) & ~(size_t)255;
    return r;
  };
  float* h = (float*)alloc((size_t)M_ * C_ * 4);
  __hip_bfloat16* hb = (__hip_bfloat16*)alloc((size_t)M_ * C_ * 2);
  __hip_bfloat16* qkv = (__hip_bfloat16*)alloc((size_t)M_ * 3 * C_ * 2);
  __hip_bfloat16* ybuf = (__hip_bfloat16*)alloc((size_t)M_ * C_ * 2);
  __hip_bfloat16* ubuf = (__hip_bfloat16*)alloc((size_t)M_ * FF_ * 2);
  float* zbuf = (float*)alloc((size_t)M_ * C_ * 4);
  __hip_bfloat16* Wt = (__hip_bfloat16*)alloc((size_t)FF_ * C_ * 2);

  dim3 blk256(256);
  embed_kernel<<<M_, blk256, 0, stream>>>(x, embed, pos, h, hb);

  for (int l = 0; l < L_; ++l) {
    transpose_cast<<<dim3(3 * C_ / 32, C_ / 32), dim3(32, 8), 0, stream>>>(
        Wqkv + (size_t)l * C_ * 3 * C_, Wt, C_, 3 * C_);
    gemm_bt<0, 1><<<dim3(3 * C_ / 128, M_ / 128), blk256, 0, stream>>>(
        hb, Wt, bqkv + (size_t)l * 3 * C_, qkv, M_, 3 * C_, C_);
    attn_mfma<<<dim3(T_ / 64, B_ * H_), blk256, 0, stream>>>(qkv, ybuf);
    transpose_cast<<<dim3(FF_ / 32, C_ / 32), dim3(32, 8), 0, stream>>>(
        W1a + (size_t)l * C_ * FF_, Wt, C_, FF_);
    gemm_bt<1, 1><<<dim3(FF_ / 128, M_ / 128), blk256, 0, stream>>>(
        ybuf, Wt, b1a + (size_t)l * FF_, ubuf, M_, FF_, C_);
    transpose_cast<<<dim3(C_ / 32, FF_ / 32), dim3(32, 8), 0, stream>>>(
        W2a + (size_t)l * FF_ * C_, Wt, FF_, C_);
    gemm_bt<0, 0><<<dim3(C_ / 128, M_ / 128), blk256, 0, stream>>>(
        ubuf, Wt, b2a + (size_t)l * C_, zbuf, M_, C_, FF_);
    resid_ln<<<M_, blk256, 0, stream>>>(h, zbuf, g1 + (size_t)l * C_,
                                        be1 + (size_t)l * C_, hb);
    transpose_cast<<<dim3(FF_ / 32, C_ / 32), dim3(32, 8), 0, stream>>>(
        W1b + (size_t)l * C_ * FF_, Wt, C_, FF_);
    gemm_bt<1, 1><<<dim3(FF_ / 128, M_ / 128), blk256, 0, stream>>>(
        hb, Wt, b1b + (size_t)l * FF_, ubuf, M_, FF_, C_);
    transpose_cast<<<dim3(C_ / 32, FF_ / 32), dim3(32, 8), 0, stream>>>(
        W2b + (size_t)l * FF_ * C_, Wt, FF_, C_);
    gemm_bt<0, 0><<<dim3(C_ / 128, M_ / 128), blk256, 0, stream>>>(
        ubuf, Wt, b2b + (size_t)l * C_, zbuf, M_, C_, FF_);
    resid_ln<<<M_, blk256, 0, stream>>>(h, zbuf, g2 + (size_t)l * C_,
                                        be2 + (size_t)l * C_, hb);
  }

  transpose_cast<<<dim3(V_ / 32, C_ / 32), dim3(32, 8), 0, stream>>>(
      lmW, Wt, C_, V_);
  gemm_bt<0, 0><<<dim3(V_ / 128, M_ / 128), blk256, 0, stream>>>(
      hb, Wt, lmb, out, M_, V_, C_);
}

// Round 3
// 4150.873 us; speedup vs baseline: 2.0180x; 1.0099x over previous
//
#include <hip/hip_runtime.h>
#include <hip/hip_bf16.h>

#define L_ 8
#define B_ 8
#define T_ 1024
#define C_ 768
#define H_ 12
#define D_HEAD 64
#define V_ 1024
#define FF_ 3072
#define M_ (B_ * T_)  // 8192 rows

typedef __bf16 bf16x8 __attribute__((ext_vector_type(8)));
typedef float f32x4 __attribute__((ext_vector_type(4)));

typedef const __attribute__((address_space(1))) void* as1cvp;
typedef __attribute__((address_space(3))) void* as3vp;

__device__ __forceinline__ void async16(const void* g, void* l) {
  __builtin_amdgcn_global_load_lds((as1cvp)g, (as3vp)l, 16, 0, 0);
}

__device__ __forceinline__ float bf2f(unsigned short u) {
  union { unsigned u32; float f; } c; c.u32 = ((unsigned)u) << 16; return c.f;
}

__device__ __forceinline__ unsigned short f2bf(float f) {
  __hip_bfloat16 h = __float2bfloat16(f);
  return *(unsigned short*)&h;
}

__device__ __forceinline__ float gelu_f(float x) {
  return 0.5f * x * (1.0f + erff(x * 0.70710678118654752f));
}

// ---------------------------------------------------------------------------
// Embedding: h[row, c] = embed[x[row]][c] + pos[row % T][c]; also bf16 copy.
// ---------------------------------------------------------------------------
__global__ __launch_bounds__(256) void embed_kernel(
    const int* __restrict__ x, const float* __restrict__ emb,
    const float* __restrict__ pos, float* __restrict__ h,
    __hip_bfloat16* __restrict__ hb) {
  int row = blockIdx.x;
  int t = row & (T_ - 1);
  int id = x[row];
#pragma unroll
  for (int j = 0; j < 3; ++j) {
    int c = threadIdx.x + j * 256;
    float v = emb[(size_t)id * C_ + c] + pos[(size_t)t * C_ + c];
    h[(size_t)row * C_ + c] = v;
    hb[(size_t)row * C_ + c] = __float2bfloat16(v);
  }
}

// ---------------------------------------------------------------------------
// Transpose + cast: W (K x N, f32) -> Wt (N x K, bf16)
// ---------------------------------------------------------------------------
__global__ void transpose_cast(const float* __restrict__ W,
                               __hip_bfloat16* __restrict__ Wt, int K, int N) {
  __shared__ float tile[32][33];
  int nb = blockIdx.x * 32, kb = blockIdx.y * 32;
  int tx = threadIdx.x, ty = threadIdx.y;  // 32 x 8
#pragma unroll
  for (int r = 0; r < 4; ++r)
    tile[ty + r * 8][tx] = W[(size_t)(kb + ty + r * 8) * N + nb + tx];
  __syncthreads();
#pragma unroll
  for (int r = 0; r < 4; ++r)
    Wt[(size_t)(nb + ty + r * 8) * K + kb + tx] =
        __float2bfloat16(tile[tx][ty + r * 8]);
}

// Two matrices of identical shape in one dispatch (z selects).
__global__ void transpose_cast2(const float* __restrict__ Wa,
                                __hip_bfloat16* __restrict__ Wta,
                                const float* __restrict__ Wb,
                                __hip_bfloat16* __restrict__ Wtb, int K, int N) {
  __shared__ float tile[32][33];
  const float* W = blockIdx.z ? Wb : Wa;
  __hip_bfloat16* Wt = blockIdx.z ? Wtb : Wta;
  int nb = blockIdx.x * 32, kb = blockIdx.y * 32;
  int tx = threadIdx.x, ty = threadIdx.y;  // 32 x 8
#pragma unroll
  for (int r = 0; r < 4; ++r)
    tile[ty + r * 8][tx] = W[(size_t)(kb + ty + r * 8) * N + nb + tx];
  __syncthreads();
#pragma unroll
  for (int r = 0; r < 4; ++r)
    Wt[(size_t)(nb + ty + r * 8) * K + kb + tx] =
        __float2bfloat16(tile[tx][ty + r * 8]);
}

// ---------------------------------------------------------------------------
// GEMM: C[M,N] = A[M,K](bf16) @ Bt[N,K](bf16)^T + bias, opt GELU, f32/bf16 out
// 128x128 tile, BK=32, 256 threads (4 waves, 2x2), mfma_f32_16x16x32_bf16.
// ---------------------------------------------------------------------------
template <int ACT_GELU, int OUT_BF16>
__global__ __launch_bounds__(256, 2) void gemm_bt(
    const __hip_bfloat16* __restrict__ A, const __hip_bfloat16* __restrict__ Bt,
    const float* __restrict__ bias, void* __restrict__ Cv, int M, int N, int K) {
  __shared__ __align__(16) __hip_bfloat16 As[128 * 32];
  __shared__ __align__(16) __hip_bfloat16 Bs[128 * 32];
  const int tid = threadIdx.x;
  const int lane = tid & 63, wv = tid >> 6;
  const int lane4 = lane & 15, quad = lane >> 4;
  const int wr = wv >> 1, wc = wv & 1;
  const int bm = blockIdx.y * 128, bn = blockIdx.x * 128;

  const int r0 = tid >> 2, kc0 = (tid & 3) * 8;
  const __hip_bfloat16* gA0 = A + (size_t)(bm + r0) * K + kc0;
  const __hip_bfloat16* gA1 = gA0 + (size_t)64 * K;
  const __hip_bfloat16* gB0 = Bt + (size_t)(bn + r0) * K + kc0;
  const __hip_bfloat16* gB1 = gB0 + (size_t)64 * K;
  __hip_bfloat16* lA0 = As + tid * 8;
  __hip_bfloat16* lA1 = As + (tid + 256) * 8;
  __hip_bfloat16* lB0 = Bs + tid * 8;
  __hip_bfloat16* lB1 = Bs + (tid + 256) * 8;

  f32x4 acc[4][4] = {};

  for (int k0 = 0; k0 < K; k0 += 32) {
    async16(gA0 + k0, lA0);
    async16(gA1 + k0, lA1);
    async16(gB0 + k0, lB0);
    async16(gB1 + k0, lB1);
    __syncthreads();
    bf16x8 af[4], bfv[4];
#pragma unroll
    for (int i = 0; i < 4; ++i)
      af[i] = *(const bf16x8*)(As + (wr * 64 + i * 16 + lane4) * 32 + quad * 8);
#pragma unroll
    for (int j = 0; j < 4; ++j)
      bfv[j] = *(const bf16x8*)(Bs + (wc * 64 + j * 16 + lane4) * 32 + quad * 8);
#pragma unroll
    for (int i = 0; i < 4; ++i)
#pragma unroll
      for (int j = 0; j < 4; ++j)
        acc[i][j] = __builtin_amdgcn_mfma_f32_16x16x32_bf16(af[i], bfv[j],
                                                            acc[i][j], 0, 0, 0);
    __syncthreads();
  }

#pragma unroll
  for (int i = 0; i < 4; ++i) {
    int row0 = bm + wr * 64 + i * 16 + quad * 4;
#pragma unroll
    for (int j = 0; j < 4; ++j) {
      int col = bn + wc * 64 + j * 16 + lane4;
      float bv = bias[col];
#pragma unroll
      for (int r = 0; r < 4; ++r) {
        float v = acc[i][j][r] + bv;
        if (ACT_GELU) v = gelu_f(v);
        size_t off = (size_t)(row0 + r) * N + col;
        if (OUT_BF16)
          ((__hip_bfloat16*)Cv)[off] = __float2bfloat16(v);
        else
          ((float*)Cv)[off] = v;
      }
    }
  }
}

// ---------------------------------------------------------------------------
// MFMA flash attention with register-prefetched K/V (software pipeline).
// Block = 64 queries of one (b,head); 4 waves x 16 queries.
// Per k-tile: issue K/V loads for kt+1, compute QK^T from regs, online
// softmax, P->LDS + V^T->LDS, PV via mfma.
// ---------------------------------------------------------------------------
__global__ __launch_bounds__(256) void attn_mfma(
    const __hip_bfloat16* __restrict__ qkv, __hip_bfloat16* __restrict__ y) {
  __shared__ __align__(16) __hip_bfloat16 VtS[64][72];    // [dim][key]
  __shared__ __align__(16) __hip_bfloat16 Ps[4][16][72];  // per wave [q][key]

  const int tid = threadIdx.x;
  const int lane = tid & 63, w = tid >> 6;
  const int lane4 = lane & 15, quad = lane >> 4;
  const int qt = gridDim.x - 1 - blockIdx.x;  // heavy tiles first
  const int bh = blockIdx.y;
  const int b = bh / H_, hh = bh % H_;
  const unsigned short* qk16 = (const unsigned short*)qkv;
  const size_t base = (size_t)b * T_ * (3 * C_) + hh * D_HEAD;

  union FragU { bf16x8 v; unsigned short s[8]; uint4 q; };

  // Q fragment (A operand), rows = qt*64 + w*16 + lane4, pre-scaled by 1/8
  FragU aq[2];
  {
    const unsigned short* qp =
        qk16 + base + (size_t)(qt * 64 + w * 16 + lane4) * (3 * C_) + C_ +
        quad * 8;
#pragma unroll
    for (int c = 0; c < 2; ++c) {
      FragU t;
      t.q = *(const uint4*)(qp + c * 32);
#pragma unroll
      for (int j = 0; j < 8; ++j) aq[c].s[j] = f2bf(bf2f(t.s[j]) * 0.125f);
    }
  }

  // per-lane constant offsets for K/V tile loads
  const unsigned short* kbase0 =
      qk16 + base + (size_t)(lane4)*(3 * C_) + quad * 8;
  const unsigned short* vbase =
      qk16 + base + (size_t)lane * (3 * C_) + 2 * C_ + w * 16;
  const size_t tile_stride = (size_t)64 * (3 * C_);

  f32x4 o_acc[4] = {};
  float m_r[4] = {-1e30f, -1e30f, -1e30f, -1e30f};
  float l_r[4] = {0.f, 0.f, 0.f, 0.f};

  FragU kc[4][2];
  uint4 vc0, vc1;
  // preload tile 0
  {
    const unsigned short* kp = kbase0;
#pragma unroll
    for (int nt = 0; nt < 4; ++nt) {
      kc[nt][0].q = *(const uint4*)(kp + nt * 16 * (3 * C_));
      kc[nt][1].q = *(const uint4*)(kp + nt * 16 * (3 * C_) + 32);
    }
    vc0 = *(const uint4*)vbase;
    vc1 = *(const uint4*)(vbase + 8);
  }

  for (int kt = 0; kt <= qt; ++kt) {
    // --- issue prefetch for next tile (clamped; independent of compute) ---
    FragU kn[4][2];
    uint4 vn0, vn1;
    {
      int ktn = (kt < qt) ? kt + 1 : qt;
      const unsigned short* kp = kbase0 + (size_t)ktn * tile_stride;
#pragma unroll
      for (int nt = 0; nt < 4; ++nt) {
        kn[nt][0].q = *(const uint4*)(kp + nt * 16 * (3 * C_));
        kn[nt][1].q = *(const uint4*)(kp + nt * 16 * (3 * C_) + 32);
      }
      const unsigned short* vp = vbase + (size_t)ktn * tile_stride;
      vn0 = *(const uint4*)vp;
      vn1 = *(const uint4*)(vp + 8);
    }

    // --- S = Q K^T from current registers ---
    f32x4 s_acc[4] = {};
#pragma unroll
    for (int nt = 0; nt < 4; ++nt) {
      s_acc[nt] = __builtin_amdgcn_mfma_f32_16x16x32_bf16(aq[0].v, kc[nt][0].v,
                                                          s_acc[nt], 0, 0, 0);
      s_acc[nt] = __builtin_amdgcn_mfma_f32_16x16x32_bf16(aq[1].v, kc[nt][1].v,
                                                          s_acc[nt], 0, 0, 0);
    }

    // --- causal mask (diagonal tile only) ---
    if (kt == qt) {
      int qloc = w * 16 + quad * 4;
#pragma unroll
      for (int nt = 0; nt < 4; ++nt) {
        int kloc = nt * 16 + lane4;
#pragma unroll
        for (int r = 0; r < 4; ++r)
          if (kloc > qloc + r) s_acc[nt][r] = -1e30f;
      }
    }

    // --- online softmax (each lane: rows quad*4+r, replicated over lane4) ---
    float p[4][4], alpha[4], ts[4];
#pragma unroll
    for (int r = 0; r < 4; ++r) {
      float tm = fmaxf(fmaxf(s_acc[0][r], s_acc[1][r]),
                       fmaxf(s_acc[2][r], s_acc[3][r]));
      tm = fmaxf(tm, __shfl_xor(tm, 1));
      tm = fmaxf(tm, __shfl_xor(tm, 2));
      tm = fmaxf(tm, __shfl_xor(tm, 4));
      tm = fmaxf(tm, __shfl_xor(tm, 8));
      float mn = fmaxf(m_r[r], tm);
      alpha[r] = __expf(m_r[r] - mn);
      m_r[r] = mn;
      float sr = 0.f;
#pragma unroll
      for (int nt = 0; nt < 4; ++nt) {
        float pv = __expf(s_acc[nt][r] - mn);
        p[nt][r] = pv;
        sr += pv;
      }
      sr += __shfl_xor(sr, 1);
      sr += __shfl_xor(sr, 2);
      sr += __shfl_xor(sr, 4);
      sr += __shfl_xor(sr, 8);
      ts[r] = sr;
    }
#pragma unroll
    for (int r = 0; r < 4; ++r) {
      l_r[r] = l_r[r] * alpha[r] + ts[r];
#pragma unroll
      for (int nt = 0; nt < 4; ++nt) o_acc[nt][r] *= alpha[r];
    }

    __syncthreads();  // prior PV reads of VtS/Ps complete

    // --- write V^T and P to LDS ---
    {
      const unsigned short* vs = (const unsigned short*)&vc0;
#pragma unroll
      for (int j = 0; j < 8; ++j)
        *(unsigned short*)&VtS[w * 16 + j][lane] = vs[j];
      vs = (const unsigned short*)&vc1;
#pragma unroll
      for (int j = 0; j < 8; ++j)
        *(unsigned short*)&VtS[w * 16 + 8 + j][lane] = vs[j];
    }
#pragma unroll
    for (int nt = 0; nt < 4; ++nt)
#pragma unroll
      for (int r = 0; r < 4; ++r)
        *(unsigned short*)&Ps[w][quad * 4 + r][nt * 16 + lane4] =
            f2bf(p[nt][r]);

    __syncthreads();  // VtS/Ps visible

    // --- O += P V ---
    FragU ap0, ap1;
    ap0.v = *(const bf16x8*)&Ps[w][lane4][quad * 8];
    ap1.v = *(const bf16x8*)&Ps[w][lane4][32 + quad * 8];
#pragma unroll
    for (int nt = 0; nt < 4; ++nt) {
      bf16x8 bv0 = *(const bf16x8*)&VtS[nt * 16 + lane4][quad * 8];
      bf16x8 bv1 = *(const bf16x8*)&VtS[nt * 16 + lane4][32 + quad * 8];
      o_acc[nt] = __builtin_amdgcn_mfma_f32_16x16x32_bf16(ap0.v, bv0,
                                                          o_acc[nt], 0, 0, 0);
      o_acc[nt] = __builtin_amdgcn_mfma_f32_16x16x32_bf16(ap1.v, bv1,
                                                          o_acc[nt], 0, 0, 0);
    }

    // --- rotate prefetched regs into current ---
#pragma unroll
    for (int nt = 0; nt < 4; ++nt) {
      kc[nt][0] = kn[nt][0];
      kc[nt][1] = kn[nt][1];
    }
    vc0 = vn0;
    vc1 = vn1;
  }

  // --- epilogue ---
  float inv[4];
#pragma unroll
  for (int r = 0; r < 4; ++r) inv[r] = 1.f / l_r[r];
#pragma unroll
  for (int nt = 0; nt < 4; ++nt) {
#pragma unroll
    for (int r = 0; r < 4; ++r) {
      int row = qt * 64 + w * 16 + quad * 4 + r;
      __hip_bfloat16* yp =
          y + (size_t)(b * T_ + row) * C_ + hh * D_HEAD + nt * 16 + lane4;
      *yp = __float2bfloat16(o_acc[nt][r] * inv[r]);
    }
  }
}

// ---------------------------------------------------------------------------
// h = h + LayerNorm(z) * g + beta ; also write bf16 copy of updated h.
// ---------------------------------------------------------------------------
__global__ __launch_bounds__(256) void resid_ln(
    float* __restrict__ h, const float* __restrict__ z,
    const float* __restrict__ g, const float* __restrict__ be,
    __hip_bfloat16* __restrict__ hb) {
  int row = blockIdx.x;
  int tid = threadIdx.x;
  const float* zr = z + (size_t)row * C_;
  float v[3], s = 0.f, s2 = 0.f;
#pragma unroll
  for (int j = 0; j < 3; ++j) {
    v[j] = zr[tid + 256 * j];
    s += v[j];
    s2 += v[j] * v[j];
  }
#pragma unroll
  for (int msk = 1; msk < 64; msk <<= 1) {
    s += __shfl_xor(s, msk);
    s2 += __shfl_xor(s2, msk);
  }
  __shared__ float red[8];
  int w = tid >> 6;
  if ((tid & 63) == 0) { red[w] = s; red[4 + w] = s2; }
  __syncthreads();
  s = red[0] + red[1] + red[2] + red[3];
  s2 = red[4] + red[5] + red[6] + red[7];
  float mu = s * (1.f / C_);
  float var = s2 * (1.f / C_) - mu * mu;
  float rstd = rsqrtf(var + 1e-5f);
  float* hr = h + (size_t)row * C_;
  __hip_bfloat16* hbr = hb + (size_t)row * C_;
#pragma unroll
  for (int j = 0; j < 3; ++j) {
    int c = tid + 256 * j;
    float nv = hr[c] + (v[j] - mu) * rstd * g[c] + be[c];
    hr[c] = nv;
    hbr[c] = __float2bfloat16(nv);
  }
}

// ---------------------------------------------------------------------------
extern "C" void kernel_launch(void* const* d_in, const int* in_sizes, int n_in,
                              void* d_out, int out_size, void* d_ws,
                              size_t ws_size, hipStream_t stream) {
  const int* x = (const int*)d_in[0];
  const float* embed = (const float*)d_in[1];
  const float* pos = (const float*)d_in[2];
  const float* Wqkv = (const float*)d_in[3];
  const float* bqkv = (const float*)d_in[4];
  const float* W1a = (const float*)d_in[5];
  const float* b1a = (const float*)d_in[6];
  const float* W2a = (const float*)d_in[7];
  const float* b2a = (const float*)d_in[8];
  const float* g1 = (const float*)d_in[9];
  const float* be1 = (const float*)d_in[10];
  const float* W1b = (const float*)d_in[11];
  const float* b1b = (const float*)d_in[12];
  const float* W2b = (const float*)d_in[13];
  const float* b2b = (const float*)d_in[14];
  const float* g2 = (const float*)d_in[15];
  const float* be2 = (const float*)d_in[16];
  const float* lmW = (const float*)d_in[17];
  const float* lmb = (const float*)d_in[18];
  float* out = (float*)d_out;

  char* p = (char*)d_ws;
  auto alloc = [&](size_t bytes) {
    void* r = (void*)p;
    p += (bytes + 255) & ~(size_t)255;
    return r;
  };
  float* h = (float*)alloc((size_t)M_ * C_ * 4);
  __hip_bfloat16* hb = (__hip_bfloat16*)alloc((size_t)M_ * C_ * 2);
  __hip_bfloat16* qkv = (__hip_bfloat16*)alloc((size_t)M_ * 3 * C_ * 2);
  __hip_bfloat16* ybuf = (__hip_bfloat16*)alloc((size_t)M_ * C_ * 2);
  __hip_bfloat16* ubuf = (__hip_bfloat16*)alloc((size_t)M_ * FF_ * 2);
  float* zbuf = (float*)alloc((size_t)M_ * C_ * 4);
  __hip_bfloat16* Wtqkv = (__hip_bfloat16*)alloc((size_t)(3 * C_) * C_ * 2);
  __hip_bfloat16* Wt1a = (__hip_bfloat16*)alloc((size_t)FF_ * C_ * 2);
  __hip_bfloat16* Wt1b = (__hip_bfloat16*)alloc((size_t)FF_ * C_ * 2);
  __hip_bfloat16* Wt2a = (__hip_bfloat16*)alloc((size_t)C_ * FF_ * 2);
  __hip_bfloat16* Wt2b = (__hip_bfloat16*)alloc((size_t)C_ * FF_ * 2);

  dim3 blk256(256);
  embed_kernel<<<M_, blk256, 0, stream>>>(x, embed, pos, h, hb);

  for (int l = 0; l < L_; ++l) {
    // all weight transposes for this layer up front (independent of h)
    transpose_cast<<<dim3(3 * C_ / 32, C_ / 32), dim3(32, 8), 0, stream>>>(
        Wqkv + (size_t)l * C_ * 3 * C_, Wtqkv, C_, 3 * C_);
    transpose_cast2<<<dim3(FF_ / 32, C_ / 32, 2), dim3(32, 8), 0, stream>>>(
        W1a + (size_t)l * C_ * FF_, Wt1a, W1b + (size_t)l * C_ * FF_, Wt1b,
        C_, FF_);
    transpose_cast2<<<dim3(C_ / 32, FF_ / 32, 2), dim3(32, 8), 0, stream>>>(
        W2a + (size_t)l * FF_ * C_, Wt2a, W2b + (size_t)l * FF_ * C_, Wt2b,
        FF_, C_);

    gemm_bt<0, 1><<<dim3(3 * C_ / 128, M_ / 128), blk256, 0, stream>>>(
        hb, Wtqkv, bqkv + (size_t)l * 3 * C_, qkv, M_, 3 * C_, C_);
    attn_mfma<<<dim3(T_ / 64, B_ * H_), blk256, 0, stream>>>(qkv, ybuf);
    gemm_bt<1, 1><<<dim3(FF_ / 128, M_ / 128), blk256, 0, stream>>>(
        ybuf, Wt1a, b1a + (size_t)l * FF_, ubuf, M_, FF_, C_);
    gemm_bt<0, 0><<<dim3(C_ / 128, M_ / 128), blk256, 0, stream>>>(
        ubuf, Wt2a, b2a + (size_t)l * C_, zbuf, M_, C_, FF_);
    resid_ln<<<M_, blk256, 0, stream>>>(h, zbuf, g1 + (size_t)l * C_,
                                        be1 + (size_t)l * C_, hb);
    gemm_bt<1, 1><<<dim3(FF_ / 128, M_ / 128), blk256, 0, stream>>>(
        hb, Wt1b, b1b + (size_t)l * FF_, ubuf, M_, FF_, C_);
    gemm_bt<0, 0><<<dim3(C_ / 128, M_ / 128), blk256, 0, stream>>>(
        ubuf, Wt2b, b2b + (size_t)l * C_, zbuf, M_, C_, FF_);
    resid_ln<<<M_, blk256, 0, stream>>>(h, zbuf, g2 + (size_t)l * C_,
                                        be2 + (size_t)l * C_, hb);
  }

  transpose_cast<<<dim3(V_ / 32, C_ / 32), dim3(32, 8), 0, stream>>>(
      lmW, Wtqkv, C_, V_);
  gemm_bt<0, 0><<<dim3(V_ / 128, M_ / 128), blk256, 0, stream>>>(
      hb, Wtqkv, lmb, out, M_, V_, C_);
}